// Round 7
// baseline (301.276 us; speedup 1.0000x reference)
//
#include <hip/hip_runtime.h>
#include <limits.h>

// Segment-argmax one-hot:
//   d_in[0] = x            float32[33554432]
//   d_in[1] = sizes        int32  [262144]   (harness delivers integers as int32!)
//   d_out   = one-hot      float32[33554432]
//
// Round-4 fix: sizes were read as int64 -> garbage offsets -> device fault.
// Harness contract: "integer -> const int*". Now read as int32.
//
// Plan:
//   K1: block-level exclusive scan of sizes (256/block) -> offs[], blocksums[]
//   K2: exclusive scan of the 1024 block sums (single block)
//   K3: one wave per segment. Segment split into scalar head (to 16B align),
//       float4 body (<=48 lanes, single pass since size<=256), scalar tail.
//       Wave butterfly argmax-reduce (first-max tie-break), then one-hot
//       write with the same head/body/tail split. x read once, out written
//       once -> ~260 MB compulsory traffic, ~41 us roofline at 6.3 TB/s.

__global__ void scan_stage1(const int* __restrict__ sizes,
                            int* __restrict__ offs,
                            int* __restrict__ blocksums, int B) {
    int tid = threadIdx.x;
    int gid = blockIdx.x * 256 + tid;
    int v = (gid < B) ? sizes[gid] : 0;
    int lane = tid & 63;
    int incl = v;
    #pragma unroll
    for (int off = 1; off < 64; off <<= 1) {
        int n = __shfl_up(incl, off, 64);
        if (lane >= off) incl += n;
    }
    __shared__ int wsum[4];
    if (lane == 63) wsum[tid >> 6] = incl;
    __syncthreads();
    int base = 0;
    int wv = tid >> 6;
    for (int i = 0; i < wv; ++i) base += wsum[i];
    if (gid < B) offs[gid] = base + incl - v;            // exclusive within block
    if (tid == 255) blocksums[blockIdx.x] = base + incl; // block total
}

__global__ void scan_stage2(int* __restrict__ blocksums, int nb) {
    int tid = threadIdx.x;   // 1024 threads, nb <= 1024
    int v = (tid < nb) ? blocksums[tid] : 0;
    int lane = tid & 63;
    int incl = v;
    #pragma unroll
    for (int off = 1; off < 64; off <<= 1) {
        int n = __shfl_up(incl, off, 64);
        if (lane >= off) incl += n;
    }
    __shared__ int wsum[16];
    if (lane == 63) wsum[tid >> 6] = incl;
    __syncthreads();
    int base = 0;
    int wv = tid >> 6;
    for (int i = 0; i < wv; ++i) base += wsum[i];
    if (tid < nb) blocksums[tid] = base + incl - v;      // in-place exclusive
}

__global__ __launch_bounds__(256) void argmax_onehot(
        const float* __restrict__ x,
        const int* __restrict__ sizes,
        const int* __restrict__ offs,
        const int* __restrict__ blockoffs,
        float* __restrict__ out, int B) {
    int w = blockIdx.x * 4 + (int)(threadIdx.x >> 6);   // wave id = segment id
    if (w >= B) return;
    int lane  = threadIdx.x & 63;
    int start = offs[w] + blockoffs[w >> 8];
    int size  = sizes[w];

    int h    = (4 - (start & 3)) & 3;   // scalar head to reach 16B alignment
    int nb   = (size - h) >> 2;         // float4 body count (<= 48 for size<=195)
    int tail = size - h - (nb << 2);    // 0..3

    float best    = -__builtin_inff();
    int   bestIdx = INT_MAX;
    // uniform combine: strict > wins; equal value -> smaller (earlier) index
    #define UPD(vv, ii) do { float _v = (vv); int _i = (ii); \
        if (_v > best || (_v == best && _i < bestIdx)) { best = _v; bestIdx = _i; } } while (0)

    if (lane < h) UPD(x[start + lane], lane);
    if (lane < nb) {
        const float4 v = *reinterpret_cast<const float4*>(x + start + h + 4 * lane);
        int li = h + 4 * lane;
        UPD(v.x, li); UPD(v.y, li + 1); UPD(v.z, li + 2); UPD(v.w, li + 3);
    }
    if (lane < tail) {
        int li = h + (nb << 2) + lane;
        UPD(x[start + li], li);
    }
    // 64-lane butterfly reduce, same tie-break
    #pragma unroll
    for (int off = 32; off >= 1; off >>= 1) {
        float ov = __shfl_xor(best, off, 64);
        int   oi = __shfl_xor(bestIdx, off, 64);
        if (ov > best || (ov == best && oi < bestIdx)) { best = ov; bestIdx = oi; }
    }
    #undef UPD

    // one-hot write: pure index compare, no re-read of x
    if (lane < h) out[start + lane] = (lane == bestIdx) ? 1.0f : 0.0f;
    if (lane < nb) {
        int li = h + 4 * lane;
        float4 o;
        o.x = (li     == bestIdx) ? 1.0f : 0.0f;
        o.y = (li + 1 == bestIdx) ? 1.0f : 0.0f;
        o.z = (li + 2 == bestIdx) ? 1.0f : 0.0f;
        o.w = (li + 3 == bestIdx) ? 1.0f : 0.0f;
        *reinterpret_cast<float4*>(out + start + h + 4 * lane) = o;
    }
    if (lane < tail) {
        int li = h + (nb << 2) + lane;
        out[start + li] = (li == bestIdx) ? 1.0f : 0.0f;
    }
}

extern "C" void kernel_launch(void* const* d_in, const int* in_sizes, int n_in,
                              void* d_out, int out_size, void* d_ws, size_t ws_size,
                              hipStream_t stream) {
    const float* x     = (const float*)d_in[0];
    const int*   sizes = (const int*)d_in[1];    // harness: integer -> const int*
    float*       out   = (float*)d_out;
    int B = in_sizes[1];

    int* offs      = (int*)d_ws;      // B ints
    int* blocksums = offs + B;        // nb1 ints

    int nb1 = (B + 255) / 256;        // 1024 for B=262144
    scan_stage1<<<nb1, 256, 0, stream>>>(sizes, offs, blocksums, B);
    scan_stage2<<<1, 1024, 0, stream>>>(blocksums, nb1);

    int blocks = (B + 3) / 4;         // 4 waves (segments) per 256-thread block
    argmax_onehot<<<blocks, 256, 0, stream>>>(x, sizes, offs, blocksums, out, B);
}

// Round 9
// 281.060 us; speedup vs baseline: 1.0719x; 1.0719x over previous
//
#include <hip/hip_runtime.h>
#include <limits.h>

// Segment-argmax one-hot:
//   d_in[0] = x       float32[33554432]
//   d_in[1] = sizes   int32  [262144]   (harness: integer -> const int*)
//   d_out   = one-hot float32[33554432]
//
// Round-8 restructure (post-mortem of first measurement: wave-per-segment was
// issue-bound at 19% HBM, 141us — butterfly shuffles + divergent phases +
// half-idle lanes cost ~100 wave-instrs per 128-elem segment):
//   K1/K2: exclusive scan of sizes (unchanged, passing, ~10us)
//   K3: dense float4 zero-fill of out (pure stream write, ~23us)
//   K4: ONE SEGMENT PER LANE serial argmax (no shuffles, no phases;
//       64 segments per wave; strict > keeps first max), then a single
//       scattered out[start+best]=1.0f per segment.

__global__ void scan_stage1(const int* __restrict__ sizes,
                            int* __restrict__ offs,
                            int* __restrict__ blocksums, int B) {
    int tid = threadIdx.x;
    int gid = blockIdx.x * 256 + tid;
    int v = (gid < B) ? sizes[gid] : 0;
    int lane = tid & 63;
    int incl = v;
    #pragma unroll
    for (int off = 1; off < 64; off <<= 1) {
        int n = __shfl_up(incl, off, 64);
        if (lane >= off) incl += n;
    }
    __shared__ int wsum[4];
    if (lane == 63) wsum[tid >> 6] = incl;
    __syncthreads();
    int base = 0;
    int wv = tid >> 6;
    for (int i = 0; i < wv; ++i) base += wsum[i];
    if (gid < B) offs[gid] = base + incl - v;            // exclusive within block
    if (tid == 255) blocksums[blockIdx.x] = base + incl; // block total
}

__global__ void scan_stage2(int* __restrict__ blocksums, int nb) {
    int tid = threadIdx.x;   // 1024 threads, nb <= 1024
    int v = (tid < nb) ? blocksums[tid] : 0;
    int lane = tid & 63;
    int incl = v;
    #pragma unroll
    for (int off = 1; off < 64; off <<= 1) {
        int n = __shfl_up(incl, off, 64);
        if (lane >= off) incl += n;
    }
    __shared__ int wsum[16];
    if (lane == 63) wsum[tid >> 6] = incl;
    __syncthreads();
    int base = 0;
    int wv = tid >> 6;
    for (int i = 0; i < wv; ++i) base += wsum[i];
    if (tid < nb) blocksums[tid] = base + incl - v;      // in-place exclusive
}

__global__ __launch_bounds__(256) void zero_fill(float4* __restrict__ out4, int n4) {
    int stride = gridDim.x * blockDim.x;
    float4 z = make_float4(0.f, 0.f, 0.f, 0.f);
    for (int i = blockIdx.x * blockDim.x + threadIdx.x; i < n4; i += stride)
        out4[i] = z;
}

__global__ __launch_bounds__(256) void argmax_scatter(
        const float* __restrict__ x,
        const int* __restrict__ sizes,
        const int* __restrict__ offs,
        const int* __restrict__ blockoffs,
        float* __restrict__ out, int B) {
    int s = blockIdx.x * 256 + threadIdx.x;   // one segment per THREAD
    if (s >= B) return;
    int start = offs[s] + blockoffs[s >> 8];  // s>>8 == blockIdx.x (wave-uniform)
    int size  = sizes[s];
    const float* p = x + start;

    float best = -__builtin_inff();
    int   bi   = 0;

    int h = (4 - (start & 3)) & 3;            // scalar head to 16B alignment
    if (h > size) h = size;
    int i = 0;
    for (; i < h; ++i) {
        float v = p[i];
        if (v > best) { best = v; bi = i; }   // strict >: keeps FIRST max
    }
    int n4 = (size - i) >> 2;                 // aligned float4 body (<=48 iters)
    const float4* p4 = reinterpret_cast<const float4*>(p + i);
    #pragma unroll 4
    for (int j = 0; j < n4; ++j) {
        float4 v = p4[j];
        int b = i + 4 * j;
        if (v.x > best) { best = v.x; bi = b;     }
        if (v.y > best) { best = v.y; bi = b + 1; }
        if (v.z > best) { best = v.z; bi = b + 2; }
        if (v.w > best) { best = v.w; bi = b + 3; }
    }
    i += n4 << 2;
    for (; i < size; ++i) {                   // scalar tail (<=3)
        float v = p[i];
        if (v > best) { best = v; bi = i; }
    }
    out[start + bi] = 1.0f;                   // single scattered store
}

extern "C" void kernel_launch(void* const* d_in, const int* in_sizes, int n_in,
                              void* d_out, int out_size, void* d_ws, size_t ws_size,
                              hipStream_t stream) {
    const float* x     = (const float*)d_in[0];
    const int*   sizes = (const int*)d_in[1];    // harness: integer -> const int*
    float*       out   = (float*)d_out;
    int B = in_sizes[1];
    int N = in_sizes[0];

    int* offs      = (int*)d_ws;      // B ints
    int* blocksums = offs + B;        // nb1 ints

    int nb1 = (B + 255) / 256;        // 1024 for B=262144
    scan_stage1<<<nb1, 256, 0, stream>>>(sizes, offs, blocksums, B);
    scan_stage2<<<1, 1024, 0, stream>>>(blocksums, nb1);

    // dense zero of out (N divisible by 4), then per-lane argmax + scatter
    zero_fill<<<2048, 256, 0, stream>>>((float4*)out, N / 4);
    int ab = (B + 255) / 256;         // 1024 blocks, 1 segment per thread
    argmax_scatter<<<ab, 256, 0, stream>>>(x, sizes, offs, blocksums, out, B);
}

// Round 10
// 264.777 us; speedup vs baseline: 1.1378x; 1.0615x over previous
//
#include <hip/hip_runtime.h>
#include <limits.h>

// Segment-argmax one-hot, round 10: fully-coalesced fused design.
//   d_in[0] = x       float32[33554432]
//   d_in[1] = sizes   int32  [262144]  (64..193, mean 128; harness: int32)
//   d_out   = one-hot float32[33554432]
//
// History: wave-per-segment = 141us (issue-bound, 19% HBM). Per-lane gather
// = ~90us argmax + 23us zero_fill (gather: 64 distinct lines per load instr).
// Now: block = 64 segments. Coalesced float4 load of the block's exact span
// into LDS (XOR-swizzled), 4 threads/segment serial argmax from LDS, zero
// LDS span + scatter 64 ones, coalesced float4 write-back. All global
// traffic streams; zero_fill kernel eliminated.
//
// LDS swizzle: word -> word ^ (((word>>7)&7)<<2). Flips bank-group bits 2-4
// only: float4s stay contiguous+aligned, permutation stays inside each
// 32-word window (array padded to 12384 words = 49.5KB -> 3 blocks/CU).

#define SW(w) ((w) ^ ((((w) >> 7) & 7) << 2))

__global__ void scan_stage1(const int* __restrict__ sizes,
                            int* __restrict__ offs,
                            int* __restrict__ blocksums, int B) {
    int tid = threadIdx.x;
    int gid = blockIdx.x * 256 + tid;
    int v = (gid < B) ? sizes[gid] : 0;
    int lane = tid & 63;
    int incl = v;
    #pragma unroll
    for (int off = 1; off < 64; off <<= 1) {
        int n = __shfl_up(incl, off, 64);
        if (lane >= off) incl += n;
    }
    __shared__ int wsum[4];
    if (lane == 63) wsum[tid >> 6] = incl;
    __syncthreads();
    int base = 0;
    int wv = tid >> 6;
    for (int i = 0; i < wv; ++i) base += wsum[i];
    if (gid < B) offs[gid] = base + incl - v;            // exclusive within 256-chunk
    if (tid == 255) blocksums[blockIdx.x] = base + incl; // chunk total
}

__global__ void scan_stage2(int* __restrict__ blocksums, int nb) {
    int tid = threadIdx.x;   // 1024 threads, nb <= 1024
    int v = (tid < nb) ? blocksums[tid] : 0;
    int lane = tid & 63;
    int incl = v;
    #pragma unroll
    for (int off = 1; off < 64; off <<= 1) {
        int n = __shfl_up(incl, off, 64);
        if (lane >= off) incl += n;
    }
    __shared__ int wsum[16];
    if (lane == 63) wsum[tid >> 6] = incl;
    __syncthreads();
    int base = 0;
    int wv = tid >> 6;
    for (int i = 0; i < wv; ++i) base += wsum[i];
    if (tid < nb) blocksums[tid] = base + incl - v;      // in-place exclusive
}

__global__ __launch_bounds__(256) void seg_onehot(
        const float* __restrict__ x,
        const int* __restrict__ sizes,
        const int* __restrict__ offs,
        const int* __restrict__ blockoffs,
        float* __restrict__ out, int B) {
    __shared__ float lds[12384];            // 49.5 KB, padded to 32-word multiple
    const int t  = threadIdx.x;
    const int s0 = blockIdx.x * 64;
    if (s0 >= B) return;
    const int lastSeg = (s0 + 63 < B) ? s0 + 63 : B - 1;

    // absolute span of this block's 64 segments (all within one 256-scan-chunk)
    const int bo     = blockoffs[s0 >> 8];
    const int s_abs  = offs[s0] + bo;
    const int e_abs  = offs[lastSeg] + bo + sizes[lastSeg];
    const int gbase  = s_abs & ~3;          // align16 down (elements)
    const int nw4    = (e_abs - gbase + 3) >> 2;   // float4s to load (<=3090)

    // ---- load: coalesced global float4 -> swizzled LDS ----
    const float4* __restrict__ x4 = reinterpret_cast<const float4*>(x + gbase);
    for (int j = t; j < nw4; j += 256) {
        float4 v = x4[j];
        int w = j << 2;
        *reinterpret_cast<float4*>(&lds[SW(w)]) = v;
    }
    __syncthreads();

    // ---- reduce: 4 threads per segment, strided serial argmax from LDS ----
    const int seg = s0 + (t >> 2);
    const int q   = t & 3;
    float best = -__builtin_inff();
    int   bi   = INT_MAX;
    int   lstart = 0;
    if (seg < B) {
        lstart = offs[seg] + bo - gbase;
        const int size = sizes[seg];
        for (int i = q; i < size; i += 4) {
            int w = lstart + i;
            float v = lds[SW(w)];
            if (v > best) { best = v; bi = i; }   // i increasing: keeps FIRST max
        }
    }
    // nibble combine (lanes 4k..4k+3 share a segment); tie -> smaller index
    #pragma unroll
    for (int off = 1; off <= 2; off <<= 1) {
        float ov = __shfl_xor(best, off, 64);
        int   oi = __shfl_xor(bi, off, 64);
        if (ov > best || (ov == best && oi < bi)) { best = ov; bi = oi; }
    }
    __syncthreads();                        // all LDS reads done before zeroing

    // ---- zero LDS span, scatter the 64 ones ----
    const float4 z = make_float4(0.f, 0.f, 0.f, 0.f);
    for (int j = t; j < nw4; j += 256) {
        int w = j << 2;
        *reinterpret_cast<float4*>(&lds[SW(w)]) = z;
    }
    __syncthreads();
    if (q == 0 && seg < B) {
        int w = lstart + bi;
        lds[SW(w)] = 1.0f;
    }
    __syncthreads();

    // ---- write-back exact span [s_abs, e_abs): head + float4 body + tail ----
    const int a4 = (s_abs + 3) & ~3;        // first 16B-aligned element
    const int e4 = e_abs & ~3;              // last aligned boundary
    const int nh = a4 - s_abs;              // 0..3 head scalars
    if (t < nh) {
        int w = s_abs - gbase + t;
        out[s_abs + t] = lds[SW(w)];
    }
    float4* __restrict__ out4 = reinterpret_cast<float4*>(out + a4);
    const int nb4 = (e4 - a4) >> 2;
    const int wb  = a4 - gbase;             // multiple of 4
    for (int j = t; j < nb4; j += 256) {
        int w = wb + (j << 2);
        out4[j] = *reinterpret_cast<const float4*>(&lds[SW(w)]);
    }
    const int nt = e_abs - e4;              // 0..3 tail scalars
    if (t < nt) {
        int w = e4 - gbase + t;
        out[e4 + t] = lds[SW(w)];
    }
}

extern "C" void kernel_launch(void* const* d_in, const int* in_sizes, int n_in,
                              void* d_out, int out_size, void* d_ws, size_t ws_size,
                              hipStream_t stream) {
    const float* x     = (const float*)d_in[0];
    const int*   sizes = (const int*)d_in[1];    // harness: integer -> const int*
    float*       out   = (float*)d_out;
    int B = in_sizes[1];

    int* offs      = (int*)d_ws;      // B ints
    int* blocksums = offs + B;        // nb1 ints

    int nb1 = (B + 255) / 256;        // 1024 for B=262144
    scan_stage1<<<nb1, 256, 0, stream>>>(sizes, offs, blocksums, B);
    scan_stage2<<<1, 1024, 0, stream>>>(blocksums, nb1);

    int blocks = (B + 63) / 64;       // 4096 blocks, 64 segments each
    seg_onehot<<<blocks, 256, 0, stream>>>(x, sizes, offs, blocksums, out, B);
}